// Round 10
// baseline (697.829 us; speedup 1.0000x reference)
//
#include <hip/hip_runtime.h>
#include <hip/hip_bf16.h>

#define N        8192
#define W        128          // 64-bit words per adjacency row
#define NCLS     5
#define NCOLS    10
#define MIN_PTS  10
#define EPS2     0.0144f      // 0.12^2
#define SENT     N

// ---- persistent device scratch (rewritten every call) ----
__device__ float4             g_pts[N];            // x, y, z, sq
__device__ int                g_cls[N];
__device__ int                g_deg[N];
__device__ int                g_parent[N];         // after k_cc: component-min ROOT directly
__device__ int                g_pointroot[N];      // component-min root per point, SENT if noise
__device__ int                g_rootlabel[N];      // cluster id for root indices
__device__ unsigned long long g_adj[N * W];        // 8 MB adjacency bitmask
__device__ unsigned long long g_coremask[W];

// ---------------- A: per-point setup + scratch init ----------------
__global__ void k_setup(const float* __restrict__ x) {
    int i = blockIdx.x * blockDim.x + threadIdx.x;
    if (i >= N) return;
    const float* r = x + i * NCOLS;
    float c0 = r[0], c1 = r[1], c2 = r[2];
    // argmax over seg cols 5..9, first max wins (matches jnp.argmax)
    float best = r[5]; int bi = 0;
#pragma unroll
    for (int c = 1; c < NCLS; ++c) {
        float v = r[5 + c];
        if (v > best) { best = v; bi = c; }
    }
    // sq = (c0^2 + c1^2) + c2^2 with NO fma contraction (match numpy elementwise+sum)
    float sq = __fadd_rn(__fadd_rn(__fmul_rn(c0, c0), __fmul_rn(c1, c1)), __fmul_rn(c2, c2));
    g_pts[i] = make_float4(c0, c1, c2, sq);
    g_cls[i] = bi;
    g_pointroot[i] = SENT;
}

// ---------------- B: adjacency bitmask + degree (one wave per row) ----------------
__global__ void k_adj() {
    int wave = threadIdx.x >> 6;             // 4 waves/block
    int lane = threadIdx.x & 63;
    int i = blockIdx.x * 4 + wave;
    float4 p = g_pts[i];
    int ci = g_cls[i];
    int deg = 0;
    for (int w = 0; w < W; ++w) {
        int j = (w << 6) + lane;             // lane-coalesced column sweep
        float4 q = g_pts[j];
        int cj = g_cls[j];
        // dot as fma chain (BLAS K=3 accumulation); 2*dot exact, one rounding on subtract
        float dot = __builtin_fmaf(p.z, q.z,
                    __builtin_fmaf(p.y, q.y,
                    __builtin_fmaf(p.x, q.x, 0.0f)));
        float d2 = (p.w + q.w) - 2.0f * dot;
        bool adjb = (d2 < EPS2) && (ci == cj);   // diagonal included (d2_ii ~ 0)
        unsigned long long word = __ballot(adjb);
        if (lane == 0) {
            g_adj[i * W + w] = word;
            deg += __popcll(word);
        }
    }
    if (lane == 0) g_deg[i] = deg;
}

// ---------------- C: pack core bitmask (grid-wide ballot) ----------------
__global__ void k_core() {
    int i = blockIdx.x * blockDim.x + threadIdx.x;
    bool c = g_deg[i] >= MIN_PTS;
    unsigned long long m = __ballot(c);
    if ((threadIdx.x & 63) == 0) g_coremask[i >> 6] = m;
}

// ---------------- D: CC in LDS, edges extracted INLINE from the bitmask ----------------
// No materialized edge list (rounds 5-7 showed any global edge staging is either
// hot-atomic-bound or gather-latency-bound from a single CU). Each wave streams
// its rows' lower-triangle adjacency words COALESCED and unites on the fly.
// Hooking larger root under smaller root => final root of each tree is the
// component minimum (exactly the reference fixpoint's value). Path-halving
// writes are benign races (parent strictly decreases toward an ancestor).
__global__ void __launch_bounds__(1024) k_cc() {
    __shared__ int sp[N];                        // 32 KB parent array
    __shared__ unsigned int s_rm[NCLS][W * 2];   // root bitmask as u32 words, 5 KB
    __shared__ unsigned long long s_core[W];
    int t = threadIdx.x;
    for (int i = t; i < N; i += 1024) sp[i] = i;
    for (int i = t; i < NCLS * W * 2; i += 1024) ((unsigned int*)s_rm)[i] = 0u;
    if (t < W) s_core[t] = g_coremask[t];
    __syncthreads();
    volatile int* vsp = sp;

    auto unite = [&](int ra, int rb) {
        for (;;) {
            for (;;) {                           // find with path halving
                int p = vsp[ra];
                if (p == ra) break;
                int gp = vsp[p];
                if (gp != p) vsp[ra] = gp;
                ra = gp;
            }
            for (;;) {
                int p = vsp[rb];
                if (p == rb) break;
                int gp = vsp[p];
                if (gp != p) vsp[rb] = gp;
                rb = gp;
            }
            if (ra == rb) return;
            int hi = ra > rb ? ra : rb;
            int lo = ra < rb ? ra : rb;
            int old = atomicCAS(&sp[hi], hi, lo);            // hook live root only
            if (old == hi) return;
            ra = old; rb = lo;
        }
    };

    // ---- edge extraction + union: wave per row, coalesced lower-triangle words ----
    int wid = t >> 6, lane = t & 63;             // 16 waves
    for (int i = wid; i < N; i += 16) {
        if (!((s_core[i >> 6] >> (i & 63)) & 1)) continue;   // i must be core
        int nw = i >> 6;                         // words holding j <= i
        for (int w = lane; w <= nw; w += 64) {   // coalesced across lanes
            unsigned long long word = g_adj[i * W + w] & s_core[w];
            int lim = i - (w << 6);
            if (lim < 64) word &= (1ull << lim) - 1;         // keep j < i (lim==0 -> 0)
            while (word) {
                int k = __builtin_ctzll(word);
                word &= word - 1;
                unite(i, (w << 6) + k);
            }
        }
    }
    __syncthreads();
    // flatten + mark roots: g_parent[i] = component-min root
    for (int i = t; i < N; i += 1024) {
        int r = i, p = sp[r];
        while (p != r) { r = p; p = sp[r]; }
        g_parent[i] = r;
        bool corei = (s_core[i >> 6] >> (i & 63)) & 1;
        if (corei && r == i)
            atomicOr(&s_rm[g_cls[i]][i >> 5], 1u << (i & 31));
    }
    __syncthreads();
    // rank roots by (class, idx): label = #roots with lexicographically smaller key
    for (int i = t; i < N; i += 1024) {
        bool corei = (s_core[i >> 6] >> (i & 63)) & 1;
        if (!corei || g_parent[i] != i) continue;
        int c = g_cls[i];
        int cnt = 0;
        for (int cc = 0; cc < c; ++cc)
            for (int w = 0; w < W * 2; ++w) cnt += __popc(s_rm[cc][w]);
        int wi = i >> 5;
        for (int w = 0; w < wi; ++w) cnt += __popc(s_rm[c][w]);
        cnt += __popc(s_rm[c][wi] & ((1u << (i & 31)) - 1u));
        g_rootlabel[i] = cnt;
    }
}

// ---------------- E: point roots ----------------
__global__ void k_pointroot() {
    __shared__ unsigned long long s_core[W];
    int t = threadIdx.x;
    if (t < W) s_core[t] = g_coremask[t];
    __syncthreads();
    int gid = blockIdx.x * blockDim.x + t;
    int i = gid >> 7, w = gid & 127;
    bool corei = (s_core[i >> 6] >> (i & 63)) & 1;
    if (corei) {
        if (w == 0) g_pointroot[i] = g_parent[i];            // already a root (flattened)
        return;
    }
    // border/noise: min over core neighbors' component roots (local min, <=1 atomic)
    unsigned long long word = g_adj[i * W + w] & s_core[w];
    if (!word) return;
    int m = SENT;
    while (word) {
        int k = __builtin_ctzll(word);
        word &= word - 1;
        int r = g_parent[(w << 6) + k];      // single load, no chain
        m = m < r ? m : r;
    }
    atomicMin(&g_pointroot[i], m);
}

// ---------------- H: emit outputs ----------------
__global__ void k_output(const float* __restrict__ x, float* __restrict__ out) {
    int i = blockIdx.x * blockDim.x + threadIdx.x;
    if (i >= N) return;
    int pr = g_pointroot[i];
    bool clustered = (pr < SENT);
    float o[6] = {0.f, 0.f, 0.f, 0.f, 0.f, 0.f};
    float lab = -1.0f;
    if (clustered) {
        lab = (float)g_rootlabel[pr];        // pr is always a root when clustered
        const float* r = x + i * NCOLS;
#pragma unroll
        for (int k = 0; k < 5; ++k) o[k] = r[k];
        o[5] = (float)g_cls[i];
    }
    float* orow = out + i * 6;
#pragma unroll
    for (int k = 0; k < 6; ++k) orow[k] = o[k];
    out[N * 6 + i] = lab;                    // labels as f32 (single-dtype flat buffer)
}

extern "C" void kernel_launch(void* const* d_in, const int* in_sizes, int n_in,
                              void* d_out, int out_size, void* d_ws, size_t ws_size,
                              hipStream_t stream) {
    const float* x = (const float*)d_in[0];
    float* out = (float*)d_out;
    (void)in_sizes; (void)n_in; (void)out_size; (void)d_ws; (void)ws_size;

    k_setup    <<<N / 256, 256, 0, stream>>>(x);
    k_adj      <<<N / 4,   256, 0, stream>>>();        // wave per row
    k_core     <<<N / 256, 256, 0, stream>>>();
    k_cc       <<<1, 1024, 0, stream>>>();
    k_pointroot<<<(N * W) / 256, 256, 0, stream>>>();
    k_output   <<<N / 256, 256, 0, stream>>>(x, out);
}

// Round 12
// 204.293 us; speedup vs baseline: 3.4158x; 3.4158x over previous
//
#include <hip/hip_runtime.h>
#include <hip/hip_bf16.h>

#define N        8192
#define W        128          // 64-bit words per adjacency row
#define NCLS     5
#define NCOLS    10
#define MIN_PTS  10
#define EPS2     0.0144f      // 0.12^2
#define SENT     N
#define NREG     64           // edge regions (spread counters)
#define CAP      8192         // edges per region (avg ~800 -> 10x headroom)
#define MAXO     (1 << 20)    // overflow edge capacity (expected ~0 used)

// ---- persistent device scratch (rewritten every call) ----
__device__ float4             g_pts[N];            // x, y, z, sq
__device__ int                g_cls[N];
__device__ int                g_deg[N];
__device__ int                g_parent[N];         // after k_cc: component-min ROOT directly
__device__ int                g_pointroot[N];      // component-min root per point, SENT if noise
__device__ int                g_rootlabel[N];      // cluster id for root indices
__device__ unsigned long long g_adj[N * W];        // 8 MB adjacency bitmask
__device__ unsigned long long g_coremask[W];
__device__ int                g_rc64[NREG * 32];   // region counters, 128B apart (no shared line)
__device__ int2               g_e64[NREG * CAP];   // 64 dense edge regions (4 MB)
__device__ int                g_ecnt;              // overflow counter (cold path)
__device__ int2               g_oedges[MAXO];      // overflow edges

// ---------------- A: per-point setup + scratch init ----------------
__global__ void k_setup(const float* __restrict__ x) {
    int i = blockIdx.x * blockDim.x + threadIdx.x;
    if (i >= N) return;
    const float* r = x + i * NCOLS;
    float c0 = r[0], c1 = r[1], c2 = r[2];
    // argmax over seg cols 5..9, first max wins (matches jnp.argmax)
    float best = r[5]; int bi = 0;
#pragma unroll
    for (int c = 1; c < NCLS; ++c) {
        float v = r[5 + c];
        if (v > best) { best = v; bi = c; }
    }
    // sq = (c0^2 + c1^2) + c2^2 with NO fma contraction (match numpy elementwise+sum)
    float sq = __fadd_rn(__fadd_rn(__fmul_rn(c0, c0), __fmul_rn(c1, c1)), __fmul_rn(c2, c2));
    g_pts[i] = make_float4(c0, c1, c2, sq);
    g_cls[i] = bi;
    g_pointroot[i] = SENT;
    if (i < NREG * 32) g_rc64[i] = 0;
    if (i == 0) g_ecnt = 0;
}

// ---------------- B: adjacency bitmask + degree (one wave per row) ----------------
__global__ void k_adj() {
    int wave = threadIdx.x >> 6;             // 4 waves/block
    int lane = threadIdx.x & 63;
    int i = blockIdx.x * 4 + wave;
    float4 p = g_pts[i];
    int ci = g_cls[i];
    int deg = 0;
    for (int w = 0; w < W; ++w) {
        int j = (w << 6) + lane;             // lane-coalesced column sweep
        float4 q = g_pts[j];
        int cj = g_cls[j];
        // dot as fma chain (BLAS K=3 accumulation); 2*dot exact, one rounding on subtract
        float dot = __builtin_fmaf(p.z, q.z,
                    __builtin_fmaf(p.y, q.y,
                    __builtin_fmaf(p.x, q.x, 0.0f)));
        float d2 = (p.w + q.w) - 2.0f * dot;
        bool adjb = (d2 < EPS2) && (ci == cj);   // diagonal included (d2_ii ~ 0)
        unsigned long long word = __ballot(adjb);
        if (lane == 0) {
            g_adj[i * W + w] = word;
            deg += __popcll(word);
        }
    }
    if (lane == 0) g_deg[i] = deg;
}

// ---------------- C: pack core bitmask (grid-wide ballot) ----------------
__global__ void k_core() {
    int i = blockIdx.x * blockDim.x + threadIdx.x;
    bool c = g_deg[i] >= MIN_PTS;
    unsigned long long m = __ballot(c);
    if ((threadIdx.x & 63) == 0) g_coremask[i >> 6] = m;
}

// ---------------- D1: extract core-core edges (j < i) into 64 DENSE regions ----------------
// Round-5 structure (its k_cc consumption measured fast) with the one measured
// flaw fixed: the single hot g_ecnt (84us of same-address atomic serialization)
// becomes 64 padded region counters -> ~256 serialized atomics per cacheline.
__global__ void k_edges() {
    __shared__ unsigned long long s_core[W];
    int t = threadIdx.x;
    if (t < W) s_core[t] = g_coremask[t];
    __syncthreads();
    int gid = blockIdx.x * blockDim.x + t;
    int i = gid >> 7, w = gid & 127;         // 2 waves per row
    int jbase = w << 6;
    unsigned long long word = 0ull;
    if (jbase < i && ((s_core[i >> 6] >> (i & 63)) & 1)) {   // i must be core, pair once
        word = g_adj[i * W + w] & s_core[w];
        int lim = i - jbase;
        if (lim < 64) word &= (1ull << lim) - 1;             // keep j < i
    }
    int cnt = __popcll(word);
    // intra-wave exclusive offsets via shuffle prefix
    int lane = t & 63;
    int pre = cnt;
#pragma unroll
    for (int d = 1; d < 64; d <<= 1) {
        int v = __shfl_up(pre, d);
        if (lane >= d) pre += v;
    }
    int total = __shfl(pre, 63);
    if (total == 0) return;
    int r = (gid >> 6) & (NREG - 1);         // region = wave id mod 64
    int base = 0;
    if (lane == 63) base = atomicAdd(&g_rc64[r * 32], total);
    base = __shfl(base, 63);
    int off = base + pre - cnt;              // exclusive slot within region
    while (word) {
        int k = __builtin_ctzll(word);
        word &= word - 1;
        if (off < CAP) {
            g_e64[r * CAP + off] = make_int2(i, jbase + k);
        } else {                             // statistical never; keeps correctness
            int o = atomicAdd(&g_ecnt, 1);
            if (o < MAXO) g_oedges[o] = make_int2(i, jbase + k);
        }
        ++off;
    }
}

// ---------------- D2: CC in LDS (single block) + cluster-id ranking ----------------
// Consumption is the round-5 measured-fast shape: DENSE arrays, lanes striding
// coalesced with independent statically-addressed loads (full MLP). One wave
// owns 4 regions. Hooking larger root under smaller => final root of each tree
// is the component minimum (the reference fixpoint's value). Path-halving
// writes are benign races (parent strictly decreases toward an ancestor);
// edge visit order varies, result (component-min) is order-independent.
__global__ void __launch_bounds__(1024) k_cc() {
    __shared__ int sp[N];                        // 32 KB parent array
    __shared__ unsigned int s_rm[NCLS][W * 2];   // root bitmask as u32 words, 5 KB
    __shared__ unsigned long long s_core[W];
    int t = threadIdx.x;
    for (int i = t; i < N; i += 1024) sp[i] = i;
    for (int i = t; i < NCLS * W * 2; i += 1024) ((unsigned int*)s_rm)[i] = 0u;
    if (t < W) s_core[t] = g_coremask[t];
    __syncthreads();
    volatile int* vsp = sp;

    auto unite = [&](int ra, int rb) {
        for (;;) {
            for (;;) {                           // find with path halving
                int p = vsp[ra];
                if (p == ra) break;
                int gp = vsp[p];
                if (gp != p) vsp[ra] = gp;
                ra = gp;
            }
            for (;;) {
                int p = vsp[rb];
                if (p == rb) break;
                int gp = vsp[p];
                if (gp != p) vsp[rb] = gp;
                rb = gp;
            }
            if (ra == rb) return;
            int hi = ra > rb ? ra : rb;
            int lo = ra < rb ? ra : rb;
            int old = atomicCAS(&sp[hi], hi, lo);            // hook live root only
            if (old == hi) return;
            ra = old; rb = lo;
        }
    };

    int wid = t >> 6, lane = t & 63;             // 16 waves x 4 regions
#pragma unroll
    for (int rr = 0; rr < NREG / 16; ++rr) {
        int r = wid * (NREG / 16) + rr;
        int cnt = g_rc64[r * 32];
        if (cnt > CAP) cnt = CAP;
        for (int e = lane; e < cnt; e += 64) {   // dense, coalesced, independent
            int2 ed = g_e64[r * CAP + e];
            unite(ed.x, ed.y);
        }
    }
    int ocnt = g_ecnt; if (ocnt > MAXO) ocnt = MAXO;
    for (int e = t; e < ocnt; e += 1024) {       // overflow edges (expected none)
        int2 ed = g_oedges[e];
        unite(ed.x, ed.y);
    }
    __syncthreads();
    // flatten + mark roots: g_parent[i] = component-min root
    for (int i = t; i < N; i += 1024) {
        int r = i, p = sp[r];
        while (p != r) { r = p; p = sp[r]; }
        g_parent[i] = r;
        bool corei = (s_core[i >> 6] >> (i & 63)) & 1;
        if (corei && r == i)
            atomicOr(&s_rm[g_cls[i]][i >> 5], 1u << (i & 31));
    }
    __syncthreads();
    // rank roots by (class, idx): label = #roots with lexicographically smaller key
    for (int i = t; i < N; i += 1024) {
        bool corei = (s_core[i >> 6] >> (i & 63)) & 1;
        if (!corei || g_parent[i] != i) continue;
        int c = g_cls[i];
        int cnt = 0;
        for (int cc = 0; cc < c; ++cc)
            for (int w = 0; w < W * 2; ++w) cnt += __popc(s_rm[cc][w]);
        int wi = i >> 5;
        for (int w = 0; w < wi; ++w) cnt += __popc(s_rm[c][w]);
        cnt += __popc(s_rm[c][wi] & ((1u << (i & 31)) - 1u));
        g_rootlabel[i] = cnt;
    }
}

// ---------------- E: point roots ----------------
__global__ void k_pointroot() {
    __shared__ unsigned long long s_core[W];
    int t = threadIdx.x;
    if (t < W) s_core[t] = g_coremask[t];
    __syncthreads();
    int gid = blockIdx.x * blockDim.x + t;
    int i = gid >> 7, w = gid & 127;
    bool corei = (s_core[i >> 6] >> (i & 63)) & 1;
    if (corei) {
        if (w == 0) g_pointroot[i] = g_parent[i];            // already a root (flattened)
        return;
    }
    // border/noise: min over core neighbors' component roots (local min, <=1 atomic)
    unsigned long long word = g_adj[i * W + w] & s_core[w];
    if (!word) return;
    int m = SENT;
    while (word) {
        int k = __builtin_ctzll(word);
        word &= word - 1;
        int r = g_parent[(w << 6) + k];      // single load, no chain
        m = m < r ? m : r;
    }
    atomicMin(&g_pointroot[i], m);
}

// ---------------- H: emit outputs ----------------
__global__ void k_output(const float* __restrict__ x, float* __restrict__ out) {
    int i = blockIdx.x * blockDim.x + threadIdx.x;
    if (i >= N) return;
    int pr = g_pointroot[i];
    bool clustered = (pr < SENT);
    float o[6] = {0.f, 0.f, 0.f, 0.f, 0.f, 0.f};
    float lab = -1.0f;
    if (clustered) {
        lab = (float)g_rootlabel[pr];        // pr is always a root when clustered
        const float* r = x + i * NCOLS;
#pragma unroll
        for (int k = 0; k < 5; ++k) o[k] = r[k];
        o[5] = (float)g_cls[i];
    }
    float* orow = out + i * 6;
#pragma unroll
    for (int k = 0; k < 6; ++k) orow[k] = o[k];
    out[N * 6 + i] = lab;                    // labels as f32 (single-dtype flat buffer)
}

extern "C" void kernel_launch(void* const* d_in, const int* in_sizes, int n_in,
                              void* d_out, int out_size, void* d_ws, size_t ws_size,
                              hipStream_t stream) {
    const float* x = (const float*)d_in[0];
    float* out = (float*)d_out;
    (void)in_sizes; (void)n_in; (void)out_size; (void)d_ws; (void)ws_size;

    k_setup    <<<N / 256, 256, 0, stream>>>(x);
    k_adj      <<<N / 4,   256, 0, stream>>>();        // wave per row
    k_core     <<<N / 256, 256, 0, stream>>>();
    k_edges    <<<(N * W) / 256, 256, 0, stream>>>();
    k_cc       <<<1, 1024, 0, stream>>>();
    k_pointroot<<<(N * W) / 256, 256, 0, stream>>>();
    k_output   <<<N / 256, 256, 0, stream>>>(x, out);
}

// Round 14
// 199.837 us; speedup vs baseline: 3.4920x; 1.0223x over previous
//
#include <hip/hip_runtime.h>
#include <hip/hip_bf16.h>

#define N        8192
#define W        128          // 64-bit words per adjacency row
#define NCLS     5
#define NCOLS    10
#define MIN_PTS  10
#define EPS2     0.0144f      // 0.12^2
#define SENT     N
#define NREG     64           // edge regions (spread counters)
#define CAP      8192         // edges per region (avg ~800 -> 10x headroom)
#define MAXO     (1 << 20)    // overflow edge capacity (expected ~0 used)

// ---- persistent device scratch (rewritten every call) ----
__device__ float4             g_pts[N];            // x, y, z, sq
__device__ int                g_cls[N];
__device__ int                g_deg[N];
__device__ int                g_parent[N];         // after k_cc: component-min ROOT directly
__device__ int                g_pointroot[N];      // component-min root per point, SENT if noise
__device__ int                g_rootlabel[N];      // cluster id for root indices
__device__ unsigned long long g_adj[N * W];        // 8 MB adjacency bitmask
__device__ unsigned long long g_coremask[W];
__device__ int                g_rc64[NREG * 32];   // region counters, 128B apart (no shared line)
__device__ int2               g_e64[NREG * CAP];   // 64 dense edge regions (4 MB)
__device__ int                g_ecnt;              // overflow counter (cold path)
__device__ int2               g_oedges[MAXO];      // overflow edges

// ---------------- A: per-point setup + scratch init ----------------
__global__ void k_setup(const float* __restrict__ x) {
    int i = blockIdx.x * blockDim.x + threadIdx.x;
    if (i >= N) return;
    const float* r = x + i * NCOLS;
    float c0 = r[0], c1 = r[1], c2 = r[2];
    // argmax over seg cols 5..9, first max wins (matches jnp.argmax)
    float best = r[5]; int bi = 0;
#pragma unroll
    for (int c = 1; c < NCLS; ++c) {
        float v = r[5 + c];
        if (v > best) { best = v; bi = c; }
    }
    // sq = (c0^2 + c1^2) + c2^2 with NO fma contraction (match numpy elementwise+sum)
    float sq = __fadd_rn(__fadd_rn(__fmul_rn(c0, c0), __fmul_rn(c1, c1)), __fmul_rn(c2, c2));
    g_pts[i] = make_float4(c0, c1, c2, sq);
    g_cls[i] = bi;
    g_pointroot[i] = SENT;
    if (i < NREG * 32) g_rc64[i] = 0;
    if (i == 0) g_ecnt = 0;
}

// ---------------- B: adjacency bitmask + degree (4 rows per wave) ----------------
// Round-12 profile: 1-row/wave version was 78us -- ~1.3GB of q-point re-reads
// from L1/L2 with exposed load latency (VALUBusy 24%, HBM 1.5%). Register-
// blocking 4 rows per wave divides the q/cls traffic by 4; per-pair numerics
// (fma chain, add/sub order) are BIT-IDENTICAL to before.
__global__ void k_adj() {
    int wave = threadIdx.x >> 6;             // 4 waves/block
    int lane = threadIdx.x & 63;
    int i0 = (blockIdx.x * 4 + wave) * 4;    // 4 consecutive rows per wave
    float4 pA = g_pts[i0 + 0], pB = g_pts[i0 + 1], pC = g_pts[i0 + 2], pD = g_pts[i0 + 3];
    int    cA = g_cls[i0 + 0], cB = g_cls[i0 + 1], cC = g_cls[i0 + 2], cD = g_cls[i0 + 3];
    int    dA = 0, dB = 0, dC = 0, dD = 0;
#pragma unroll 2
    for (int w = 0; w < W; ++w) {
        int j = (w << 6) + lane;             // lane-coalesced column sweep
        float4 q = g_pts[j];                 // ONE load serves 4 rows
        int cj = g_cls[j];
#define ADJ_ROW(P, CI, DI)                                                      \
        {                                                                       \
            float dot = __builtin_fmaf(P.z, q.z,                                \
                        __builtin_fmaf(P.y, q.y,                                \
                        __builtin_fmaf(P.x, q.x, 0.0f)));                       \
            float d2v = (P.w + q.w) - 2.0f * dot;                               \
            bool adjb = (d2v < EPS2) && (CI == cj);                             \
            unsigned long long word = __ballot(adjb);                           \
            if (lane == (DI)) { /* spread the 4 stores across 4 lanes */        \
                g_adj[(size_t)(i0 + (DI)) * W + w] = word;                      \
            }                                                                   \
            if (lane == 0) {                                                    \
                (DI) == 0 ? dA += __popcll(word) :                              \
                (DI) == 1 ? dB += __popcll(word) :                              \
                (DI) == 2 ? dC += __popcll(word) : (dD += __popcll(word));      \
            }                                                                   \
        }
        ADJ_ROW(pA, cA, 0)
        ADJ_ROW(pB, cB, 1)
        ADJ_ROW(pC, cC, 2)
        ADJ_ROW(pD, cD, 3)
#undef ADJ_ROW
    }
    if (lane == 0) {
        g_deg[i0 + 0] = dA; g_deg[i0 + 1] = dB;
        g_deg[i0 + 2] = dC; g_deg[i0 + 3] = dD;
    }
}

// ---------------- C: pack core bitmask (grid-wide ballot) ----------------
__global__ void k_core() {
    int i = blockIdx.x * blockDim.x + threadIdx.x;
    bool c = g_deg[i] >= MIN_PTS;
    unsigned long long m = __ballot(c);
    if ((threadIdx.x & 63) == 0) g_coremask[i >> 6] = m;
}

// ---------------- D1: extract core-core edges (j < i) into 64 DENSE regions ----------------
__global__ void k_edges() {
    __shared__ unsigned long long s_core[W];
    int t = threadIdx.x;
    if (t < W) s_core[t] = g_coremask[t];
    __syncthreads();
    int gid = blockIdx.x * blockDim.x + t;
    int i = gid >> 7, w = gid & 127;         // 2 waves per row
    int jbase = w << 6;
    unsigned long long word = 0ull;
    if (jbase < i && ((s_core[i >> 6] >> (i & 63)) & 1)) {   // i must be core, pair once
        word = g_adj[i * W + w] & s_core[w];
        int lim = i - jbase;
        if (lim < 64) word &= (1ull << lim) - 1;             // keep j < i
    }
    int cnt = __popcll(word);
    // intra-wave exclusive offsets via shuffle prefix
    int lane = t & 63;
    int pre = cnt;
#pragma unroll
    for (int d = 1; d < 64; d <<= 1) {
        int v = __shfl_up(pre, d);
        if (lane >= d) pre += v;
    }
    int total = __shfl(pre, 63);
    if (total == 0) return;
    int r = (gid >> 6) & (NREG - 1);         // region = wave id mod 64
    int base = 0;
    if (lane == 63) base = atomicAdd(&g_rc64[r * 32], total);
    base = __shfl(base, 63);
    int off = base + pre - cnt;              // exclusive slot within region
    while (word) {
        int k = __builtin_ctzll(word);
        word &= word - 1;
        if (off < CAP) {
            g_e64[r * CAP + off] = make_int2(i, jbase + k);
        } else {                             // statistical never; keeps correctness
            int o = atomicAdd(&g_ecnt, 1);
            if (o < MAXO) g_oedges[o] = make_int2(i, jbase + k);
        }
        ++off;
    }
}

// ---------------- D2: CC in LDS (single block) + cluster-id ranking ----------------
__global__ void __launch_bounds__(1024) k_cc() {
    __shared__ int sp[N];                        // 32 KB parent array
    __shared__ unsigned int s_rm[NCLS][W * 2];   // root bitmask as u32 words, 5 KB
    __shared__ unsigned long long s_core[W];
    int t = threadIdx.x;
    for (int i = t; i < N; i += 1024) sp[i] = i;
    for (int i = t; i < NCLS * W * 2; i += 1024) ((unsigned int*)s_rm)[i] = 0u;
    if (t < W) s_core[t] = g_coremask[t];
    __syncthreads();
    volatile int* vsp = sp;

    auto unite = [&](int ra, int rb) {
        for (;;) {
            for (;;) {                           // find with path halving
                int p = vsp[ra];
                if (p == ra) break;
                int gp = vsp[p];
                if (gp != p) vsp[ra] = gp;
                ra = gp;
            }
            for (;;) {
                int p = vsp[rb];
                if (p == rb) break;
                int gp = vsp[p];
                if (gp != p) vsp[rb] = gp;
                rb = gp;
            }
            if (ra == rb) return;
            int hi = ra > rb ? ra : rb;
            int lo = ra < rb ? ra : rb;
            int old = atomicCAS(&sp[hi], hi, lo);            // hook live root only
            if (old == hi) return;
            ra = old; rb = lo;
        }
    };

    int wid = t >> 6, lane = t & 63;             // 16 waves x 4 regions
#pragma unroll
    for (int rr = 0; rr < NREG / 16; ++rr) {
        int r = wid * (NREG / 16) + rr;
        int cnt = g_rc64[r * 32];
        if (cnt > CAP) cnt = CAP;
        for (int e = lane; e < cnt; e += 64) {   // dense, coalesced, independent
            int2 ed = g_e64[r * CAP + e];
            unite(ed.x, ed.y);
        }
    }
    int ocnt = g_ecnt; if (ocnt > MAXO) ocnt = MAXO;
    for (int e = t; e < ocnt; e += 1024) {       // overflow edges (expected none)
        int2 ed = g_oedges[e];
        unite(ed.x, ed.y);
    }
    __syncthreads();
    // flatten + mark roots: g_parent[i] = component-min root
    for (int i = t; i < N; i += 1024) {
        int r = i, p = sp[r];
        while (p != r) { r = p; p = sp[r]; }
        g_parent[i] = r;
        bool corei = (s_core[i >> 6] >> (i & 63)) & 1;
        if (corei && r == i)
            atomicOr(&s_rm[g_cls[i]][i >> 5], 1u << (i & 31));
    }
    __syncthreads();
    // rank roots by (class, idx): label = #roots with lexicographically smaller key
    for (int i = t; i < N; i += 1024) {
        bool corei = (s_core[i >> 6] >> (i & 63)) & 1;
        if (!corei || g_parent[i] != i) continue;
        int c = g_cls[i];
        int cnt = 0;
        for (int cc = 0; cc < c; ++cc)
            for (int w = 0; w < W * 2; ++w) cnt += __popc(s_rm[cc][w]);
        int wi = i >> 5;
        for (int w = 0; w < wi; ++w) cnt += __popc(s_rm[c][w]);
        cnt += __popc(s_rm[c][wi] & ((1u << (i & 31)) - 1u));
        g_rootlabel[i] = cnt;
    }
}

// ---------------- E: point roots ----------------
__global__ void k_pointroot() {
    __shared__ unsigned long long s_core[W];
    int t = threadIdx.x;
    if (t < W) s_core[t] = g_coremask[t];
    __syncthreads();
    int gid = blockIdx.x * blockDim.x + t;
    int i = gid >> 7, w = gid & 127;
    bool corei = (s_core[i >> 6] >> (i & 63)) & 1;
    if (corei) {
        if (w == 0) g_pointroot[i] = g_parent[i];            // already a root (flattened)
        return;
    }
    // border/noise: min over core neighbors' component roots (local min, <=1 atomic)
    unsigned long long word = g_adj[i * W + w] & s_core[w];
    if (!word) return;
    int m = SENT;
    while (word) {
        int k = __builtin_ctzll(word);
        word &= word - 1;
        int r = g_parent[(w << 6) + k];      // single load, no chain
        m = m < r ? m : r;
    }
    atomicMin(&g_pointroot[i], m);
}

// ---------------- H: emit outputs ----------------
__global__ void k_output(const float* __restrict__ x, float* __restrict__ out) {
    int i = blockIdx.x * blockDim.x + threadIdx.x;
    if (i >= N) return;
    int pr = g_pointroot[i];
    bool clustered = (pr < SENT);
    float o[6] = {0.f, 0.f, 0.f, 0.f, 0.f, 0.f};
    float lab = -1.0f;
    if (clustered) {
        lab = (float)g_rootlabel[pr];        // pr is always a root when clustered
        const float* r = x + i * NCOLS;
#pragma unroll
        for (int k = 0; k < 5; ++k) o[k] = r[k];
        o[5] = (float)g_cls[i];
    }
    float* orow = out + i * 6;
#pragma unroll
    for (int k = 0; k < 6; ++k) orow[k] = o[k];
    out[N * 6 + i] = lab;                    // labels as f32 (single-dtype flat buffer)
}

extern "C" void kernel_launch(void* const* d_in, const int* in_sizes, int n_in,
                              void* d_out, int out_size, void* d_ws, size_t ws_size,
                              hipStream_t stream) {
    const float* x = (const float*)d_in[0];
    float* out = (float*)d_out;
    (void)in_sizes; (void)n_in; (void)out_size; (void)d_ws; (void)ws_size;

    k_setup    <<<N / 256, 256, 0, stream>>>(x);
    k_adj      <<<N / 16,  256, 0, stream>>>();        // 4 waves/block x 4 rows/wave
    k_core     <<<N / 256, 256, 0, stream>>>();
    k_edges    <<<(N * W) / 256, 256, 0, stream>>>();
    k_cc       <<<1, 1024, 0, stream>>>();
    k_pointroot<<<(N * W) / 256, 256, 0, stream>>>();
    k_output   <<<N / 256, 256, 0, stream>>>(x, out);
}

// Round 18
// 177.601 us; speedup vs baseline: 3.9292x; 1.1252x over previous
//
#include <hip/hip_runtime.h>
#include <hip/hip_bf16.h>

#define N        8192
#define W        128          // 64-bit words per adjacency row
#define NCLS     5
#define NCOLS    10
#define MIN_PTS  10
#define EPS2     0.0144f      // 0.12^2
#define SENT     N
#define NREG     64           // edge regions (spread counters)
#define CAP      8192         // edges per region (avg ~800 -> 10x headroom)
#define MAXO     (1 << 20)    // overflow edge capacity (expected ~0 used)
#define TILE     2048         // q-points staged in LDS per tile (40 KB)

// ---- persistent device scratch (rewritten every call) ----
__device__ float4             g_pts[N];            // x, y, z, sq
__device__ int                g_cls[N];
__device__ int                g_deg[N];
__device__ int                g_parent[N];         // after k_cc: component-min ROOT directly
__device__ int                g_pointroot[N];      // component-min root per point, SENT if noise
__device__ int                g_rootlabel[N];      // cluster id for root indices
__device__ unsigned long long g_adj[N * W];        // 8 MB adjacency bitmask
__device__ unsigned long long g_coremask[W];
__device__ int                g_rc64[NREG * 32];   // region counters, 128B apart (no shared line)
__device__ int2               g_e64[NREG * CAP];   // 64 dense edge regions (4 MB)
__device__ int                g_ecnt;              // overflow counter (cold path)
__device__ int2               g_oedges[MAXO];      // overflow edges

// ---------------- A: per-point setup + scratch init ----------------
__global__ void k_setup(const float* __restrict__ x) {
    int i = blockIdx.x * blockDim.x + threadIdx.x;
    if (i >= N) return;
    const float* r = x + i * NCOLS;
    float c0 = r[0], c1 = r[1], c2 = r[2];
    // argmax over seg cols 5..9, first max wins (matches jnp.argmax)
    float best = r[5]; int bi = 0;
#pragma unroll
    for (int c = 1; c < NCLS; ++c) {
        float v = r[5 + c];
        if (v > best) { best = v; bi = c; }
    }
    // sq = (c0^2 + c1^2) + c2^2 with NO fma contraction (match numpy elementwise+sum)
    float sq = __fadd_rn(__fadd_rn(__fmul_rn(c0, c0), __fmul_rn(c1, c1)), __fmul_rn(c2, c2));
    g_pts[i] = make_float4(c0, c1, c2, sq);
    g_cls[i] = bi;
    g_pointroot[i] = SENT;
    if (i < NREG * 32) g_rc64[i] = 0;
    if (i == 0) g_ecnt = 0;
}

// ---------------- B: adjacency bitmask + degree (LDS-staged q-points) ----------------
// r12/r14 measured: VALU floor ~19us; the rest was exposed L2 latency on the
// inner-loop g_pts[j] load (r14: VALUBusy 27%, occ 21%). Staging q-points in
// LDS tiles replaces the ~200cy L2 latency with pipelined ds_reads; the
// per-pair arithmetic reads identical bits -> adjacency is BIT-IDENTICAL.
__global__ void __launch_bounds__(256) k_adj() {
    __shared__ float4 s_pts[TILE];           // 32 KB
    __shared__ int    s_cls[TILE];           //  8 KB
    int wave = threadIdx.x >> 6;             // 4 waves/block
    int lane = threadIdx.x & 63;
    int i0 = (blockIdx.x * 4 + wave) * 4;    // 4 consecutive rows per wave
    float4 pA = g_pts[i0 + 0], pB = g_pts[i0 + 1], pC = g_pts[i0 + 2], pD = g_pts[i0 + 3];
    int    cA = g_cls[i0 + 0], cB = g_cls[i0 + 1], cC = g_cls[i0 + 2], cD = g_cls[i0 + 3];
    int    dA = 0, dB = 0, dC = 0, dD = 0;
    for (int tile = 0; tile < N; tile += TILE) {
        // cooperative coalesced stage (256 threads x 8 points)
        for (int k = threadIdx.x; k < TILE; k += 256) {
            s_pts[k] = g_pts[tile + k];
            s_cls[k] = g_cls[tile + k];
        }
        __syncthreads();
        int wbase = tile >> 6;               // global 64-bit-word offset
#pragma unroll 2
        for (int w = 0; w < TILE / 64; ++w) {
            float4 q = s_pts[(w << 6) + lane];
            int   cj = s_cls[(w << 6) + lane];
#define ADJ_ROW(P, CI, DI)                                                      \
            {                                                                   \
                float dot = __builtin_fmaf(P.z, q.z,                            \
                            __builtin_fmaf(P.y, q.y,                            \
                            __builtin_fmaf(P.x, q.x, 0.0f)));                   \
                float d2v = (P.w + q.w) - 2.0f * dot;                           \
                bool adjb = (d2v < EPS2) && (CI == cj);                         \
                unsigned long long word = __ballot(adjb);                       \
                if (lane == (DI)) {                                             \
                    g_adj[(size_t)(i0 + (DI)) * W + wbase + w] = word;          \
                }                                                               \
                if (lane == 0) {                                                \
                    (DI) == 0 ? dA += __popcll(word) :                          \
                    (DI) == 1 ? dB += __popcll(word) :                          \
                    (DI) == 2 ? dC += __popcll(word) : (dD += __popcll(word));  \
                }                                                               \
            }
            ADJ_ROW(pA, cA, 0)
            ADJ_ROW(pB, cB, 1)
            ADJ_ROW(pC, cC, 2)
            ADJ_ROW(pD, cD, 3)
#undef ADJ_ROW
        }
        __syncthreads();
    }
    if (lane == 0) {
        g_deg[i0 + 0] = dA; g_deg[i0 + 1] = dB;
        g_deg[i0 + 2] = dC; g_deg[i0 + 3] = dD;
    }
}

// ---------------- C: pack core bitmask (grid-wide ballot) ----------------
__global__ void k_core() {
    int i = blockIdx.x * blockDim.x + threadIdx.x;
    bool c = g_deg[i] >= MIN_PTS;
    unsigned long long m = __ballot(c);
    if ((threadIdx.x & 63) == 0) g_coremask[i >> 6] = m;
}

// ---------------- D1: extract core-core edges (j < i) into 64 DENSE regions ----------------
__global__ void k_edges() {
    __shared__ unsigned long long s_core[W];
    int t = threadIdx.x;
    if (t < W) s_core[t] = g_coremask[t];
    __syncthreads();
    int gid = blockIdx.x * blockDim.x + t;
    int i = gid >> 7, w = gid & 127;         // 2 waves per row
    int jbase = w << 6;
    unsigned long long word = 0ull;
    if (jbase < i && ((s_core[i >> 6] >> (i & 63)) & 1)) {   // i must be core, pair once
        word = g_adj[i * W + w] & s_core[w];
        int lim = i - jbase;
        if (lim < 64) word &= (1ull << lim) - 1;             // keep j < i
    }
    int cnt = __popcll(word);
    // intra-wave exclusive offsets via shuffle prefix
    int lane = t & 63;
    int pre = cnt;
#pragma unroll
    for (int d = 1; d < 64; d <<= 1) {
        int v = __shfl_up(pre, d);
        if (lane >= d) pre += v;
    }
    int total = __shfl(pre, 63);
    if (total == 0) return;
    int r = (gid >> 6) & (NREG - 1);         // region = wave id mod 64
    int base = 0;
    if (lane == 63) base = atomicAdd(&g_rc64[r * 32], total);
    base = __shfl(base, 63);
    int off = base + pre - cnt;              // exclusive slot within region
    while (word) {
        int k = __builtin_ctzll(word);
        word &= word - 1;
        if (off < CAP) {
            g_e64[r * CAP + off] = make_int2(i, jbase + k);
        } else {                             // statistical never; keeps correctness
            int o = atomicAdd(&g_ecnt, 1);
            if (o < MAXO) g_oedges[o] = make_int2(i, jbase + k);
        }
        ++off;
    }
}

// ---------------- D2: CC in LDS (single block) + cluster-id ranking ----------------
__global__ void __launch_bounds__(1024) k_cc() {
    __shared__ int sp[N];                        // 32 KB parent array
    __shared__ unsigned int s_rm[NCLS][W * 2];   // root bitmask as u32 words, 5 KB
    __shared__ unsigned long long s_core[W];
    int t = threadIdx.x;
    for (int i = t; i < N; i += 1024) sp[i] = i;
    for (int i = t; i < NCLS * W * 2; i += 1024) ((unsigned int*)s_rm)[i] = 0u;
    if (t < W) s_core[t] = g_coremask[t];
    __syncthreads();
    volatile int* vsp = sp;

    auto unite = [&](int ra, int rb) {
        for (;;) {
            for (;;) {                           // find with path halving
                int p = vsp[ra];
                if (p == ra) break;
                int gp = vsp[p];
                if (gp != p) vsp[ra] = gp;
                ra = gp;
            }
            for (;;) {
                int p = vsp[rb];
                if (p == rb) break;
                int gp = vsp[p];
                if (gp != p) vsp[rb] = gp;
                rb = gp;
            }
            if (ra == rb) return;
            int hi = ra > rb ? ra : rb;
            int lo = ra < rb ? ra : rb;
            int old = atomicCAS(&sp[hi], hi, lo);            // hook live root only
            if (old == hi) return;
            ra = old; rb = lo;
        }
    };

    int wid = t >> 6, lane = t & 63;             // 16 waves x 4 regions
#pragma unroll
    for (int rr = 0; rr < NREG / 16; ++rr) {
        int r = wid * (NREG / 16) + rr;
        int cnt = g_rc64[r * 32];
        if (cnt > CAP) cnt = CAP;
        for (int e = lane; e < cnt; e += 64) {   // dense, coalesced, independent
            int2 ed = g_e64[r * CAP + e];
            unite(ed.x, ed.y);
        }
    }
    int ocnt = g_ecnt; if (ocnt > MAXO) ocnt = MAXO;
    for (int e = t; e < ocnt; e += 1024) {       // overflow edges (expected none)
        int2 ed = g_oedges[e];
        unite(ed.x, ed.y);
    }
    __syncthreads();
    // flatten + mark roots: g_parent[i] = component-min root
    for (int i = t; i < N; i += 1024) {
        int r = i, p = sp[r];
        while (p != r) { r = p; p = sp[r]; }
        g_parent[i] = r;
        bool corei = (s_core[i >> 6] >> (i & 63)) & 1;
        if (corei && r == i)
            atomicOr(&s_rm[g_cls[i]][i >> 5], 1u << (i & 31));
    }
    __syncthreads();
    // rank roots by (class, idx): label = #roots with lexicographically smaller key
    for (int i = t; i < N; i += 1024) {
        bool corei = (s_core[i >> 6] >> (i & 63)) & 1;
        if (!corei || g_parent[i] != i) continue;
        int c = g_cls[i];
        int cnt = 0;
        for (int cc = 0; cc < c; ++cc)
            for (int w = 0; w < W * 2; ++w) cnt += __popc(s_rm[cc][w]);
        int wi = i >> 5;
        for (int w = 0; w < wi; ++w) cnt += __popc(s_rm[c][w]);
        cnt += __popc(s_rm[c][wi] & ((1u << (i & 31)) - 1u));
        g_rootlabel[i] = cnt;
    }
}

// ---------------- E: point roots ----------------
__global__ void k_pointroot() {
    __shared__ unsigned long long s_core[W];
    int t = threadIdx.x;
    if (t < W) s_core[t] = g_coremask[t];
    __syncthreads();
    int gid = blockIdx.x * blockDim.x + t;
    int i = gid >> 7, w = gid & 127;
    bool corei = (s_core[i >> 6] >> (i & 63)) & 1;
    if (corei) {
        if (w == 0) g_pointroot[i] = g_parent[i];            // already a root (flattened)
        return;
    }
    // border/noise: min over core neighbors' component roots (local min, <=1 atomic)
    unsigned long long word = g_adj[i * W + w] & s_core[w];
    if (!word) return;
    int m = SENT;
    while (word) {
        int k = __builtin_ctzll(word);
        word &= word - 1;
        int r = g_parent[(w << 6) + k];      // single load, no chain
        m = m < r ? m : r;
    }
    atomicMin(&g_pointroot[i], m);
}

// ---------------- H: emit outputs ----------------
__global__ void k_output(const float* __restrict__ x, float* __restrict__ out) {
    int i = blockIdx.x * blockDim.x + threadIdx.x;
    if (i >= N) return;
    int pr = g_pointroot[i];
    bool clustered = (pr < SENT);
    float o[6] = {0.f, 0.f, 0.f, 0.f, 0.f, 0.f};
    float lab = -1.0f;
    if (clustered) {
        lab = (float)g_rootlabel[pr];        // pr is always a root when clustered
        const float* r = x + i * NCOLS;
#pragma unroll
        for (int k = 0; k < 5; ++k) o[k] = r[k];
        o[5] = (float)g_cls[i];
    }
    float* orow = out + i * 6;
#pragma unroll
    for (int k = 0; k < 6; ++k) orow[k] = o[k];
    out[N * 6 + i] = lab;                    // labels as f32 (single-dtype flat buffer)
}

extern "C" void kernel_launch(void* const* d_in, const int* in_sizes, int n_in,
                              void* d_out, int out_size, void* d_ws, size_t ws_size,
                              hipStream_t stream) {
    const float* x = (const float*)d_in[0];
    float* out = (float*)d_out;
    (void)in_sizes; (void)n_in; (void)out_size; (void)d_ws; (void)ws_size;

    k_setup    <<<N / 256, 256, 0, stream>>>(x);
    k_adj      <<<N / 16,  256, 0, stream>>>();        // 4 waves/block x 4 rows/wave, LDS tiles
    k_core     <<<N / 256, 256, 0, stream>>>();
    k_edges    <<<(N * W) / 256, 256, 0, stream>>>();
    k_cc       <<<1, 1024, 0, stream>>>();
    k_pointroot<<<(N * W) / 256, 256, 0, stream>>>();
    k_output   <<<N / 256, 256, 0, stream>>>(x, out);
}